// Round 13
// baseline (52.550 us; speedup 1.0000x reference)
//
#include <hip/hip_runtime.h>

#define NN 50000
#define NE 100000
#define NREL 64
#define D 64
#define RCAP 1280      // per-relation bucket capacity (expected ~676)
#define CSTR 16        // cursor stride in ints (64 B per counter)
#define RB2  20        // group-blocks per relation (covers RCAP/64)
#define SCAT_BLOCKS ((NE + 255) / 256)     // 391
#define DENSE_BLOCKS ((NN + 63) / 64)      // 782
#define FILL_BLOCKS 128
#define FILL_ITERS  2

typedef unsigned long long u64;

// ws layout (bytes): packed [0,400000) | cursor @512K | rbucket @520K
#define WS_CURSOR  (512 * 1024)
#define WS_RBUCKET (520 * 1024)

__global__ void k_init(u64* __restrict__ packed, int* __restrict__ cursor) {
    int t = blockIdx.x * blockDim.x + threadIdx.x;
    for (int i = t; i < NN; i += gridDim.x * blockDim.x) packed[i] = 0ull;
    if (t < 64) cursor[t * CSTR] = 0;
}

__device__ __forceinline__ float elem(const float4& v, int k) {
    return (k == 0) ? v.x : (k == 1) ? v.y : (k == 2) ? v.z : v.w;
}

// fused: blocks [0,SCAT_BLOCKS) scatter edges via 64-bit atomicMax;
// blocks [SCAT_BLOCKS, +DENSE_BLOCKS) compute dense out[v] = h[v] @ WS.
__global__ __launch_bounds__(256) void k_scatter_dense(
    const int* __restrict__ edges, const float* __restrict__ h,
    const float* __restrict__ wself, u64* __restrict__ packed,
    float* __restrict__ out)
{
    __shared__ float lds_ws[D * D];

    if (blockIdx.x < SCAT_BLOCKS) {
        int e = blockIdx.x * 256 + threadIdx.x;
        if (e < NE) {
            int s = edges[e * 3 + 0];
            int r = edges[e * 3 + 1];
            int d = edges[e * 3 + 2];
            u64 key = ((u64)(e + 1) << 22) | ((u64)r << 16) | (u64)s;
            atomicMax(&packed[d], key);
        }
        return;
    }

    // ---- dense self-loop GEMM ----
    {
        const float4* __restrict__ WS4 = reinterpret_cast<const float4*>(wself);
        #pragma unroll
        for (int k = 0; k < 4; ++k)
            reinterpret_cast<float4*>(lds_ws)[k * 256 + threadIdx.x] = WS4[k * 256 + threadIdx.x];
    }
    __syncthreads();

    const int lane = threadIdx.x & 63;
    const int wv   = threadIdx.x >> 6;          // o-quarter
    const int v    = (blockIdx.x - SCAT_BLOCKS) * 64 + lane;
    const int vc   = min(v, NN - 1);
    const int obase = wv * 16;

    const float4* __restrict__ hsrc = reinterpret_cast<const float4*>(h + (size_t)vc * D);
    float4 hreg[16];
    #pragma unroll
    for (int k = 0; k < 16; ++k) hreg[k] = hsrc[k];

    float acc[16];
    #pragma unroll
    for (int oo = 0; oo < 16; ++oo) acc[oo] = 0.f;

    #pragma unroll
    for (int i4 = 0; i4 < 16; ++i4) {
        #pragma unroll
        for (int ii = 0; ii < 4; ++ii) {
            const float hb = elem(hreg[i4], ii);
            const float4* __restrict__ wsr =
                reinterpret_cast<const float4*>(&lds_ws[(i4 * 4 + ii) * D + obase]);  // uniform -> broadcast
            #pragma unroll
            for (int q = 0; q < 4; ++q) {
                const float4 w = wsr[q];
                acc[q * 4 + 0] = fmaf(hb, w.x, acc[q * 4 + 0]);
                acc[q * 4 + 1] = fmaf(hb, w.y, acc[q * 4 + 1]);
                acc[q * 4 + 2] = fmaf(hb, w.z, acc[q * 4 + 2]);
                acc[q * 4 + 3] = fmaf(hb, w.w, acc[q * 4 + 3]);
            }
        }
    }

    if (v < NN) {
        float4* __restrict__ orow = reinterpret_cast<float4*>(out + (size_t)v * D + obase);
        #pragma unroll
        for (int q = 0; q < 4; ++q)
            orow[q] = make_float4(acc[q * 4], acc[q * 4 + 1], acc[q * 4 + 2], acc[q * 4 + 3]);
    }
}

// block-aggregated bucket fill (rel nodes only)
__global__ __launch_bounds__(256) void k_fill(
    const u64* __restrict__ packed, int* __restrict__ cursor,
    unsigned* __restrict__ rbucket)
{
    __shared__ int hcnt[64];
    __shared__ int hbase[64];
    const int t = threadIdx.x;
    if (t < 64) hcnt[t] = 0;
    __syncthreads();

    int      myr[FILL_ITERS];
    int      myslot[FILL_ITERS];
    unsigned myent[FILL_ITERS];

    #pragma unroll
    for (int it = 0; it < FILL_ITERS; ++it) {
        const int v = (blockIdx.x * FILL_ITERS + it) * 256 + t;
        myr[it] = -1;
        if (v < NN) {
            u64 key = packed[v];
            if (key) {
                myr[it]   = (int)((key >> 16) & 63);
                myent[it] = ((unsigned)v << 16) | (unsigned)(key & 0xFFFF);
                myslot[it] = atomicAdd(&hcnt[myr[it]], 1);
            }
        }
    }
    __syncthreads();
    if (t < 64 && hcnt[t] > 0)
        hbase[t] = atomicAdd(&cursor[t * CSTR], hcnt[t]);
    __syncthreads();

    #pragma unroll
    for (int it = 0; it < FILL_ITERS; ++it) {
        const int r = myr[it];
        if (r >= 0) {
            const int p = hbase[r] + myslot[it];
            if (p < RCAP) rbucket[r * RCAP + p] = myent[it];
        }
    }
}

// scattered rel pass: out[v] += h[src] @ W[r]   (single writer per v,o across grid)
__global__ __launch_bounds__(256) void k_rel(
    const float* __restrict__ h, const float* __restrict__ weight,
    const unsigned* __restrict__ rbucket, const int* __restrict__ cursor,
    float* __restrict__ out)
{
    __shared__ float lds_w[D * D];   // W[r] 16 KiB

    const int lane = threadIdx.x & 63;
    const int wv   = threadIdx.x >> 6;          // o-quarter
    const int r    = blockIdx.x / RB2;
    const int grp  = blockIdx.x % RB2;
    const int cnt  = min(cursor[r * CSTR], RCAP);
    if (grp * 64 >= cnt) return;                // block-uniform, before sync

    {
        const float4* __restrict__ W4 = reinterpret_cast<const float4*>(weight + (size_t)r * D * D);
        #pragma unroll
        for (int k = 0; k < 4; ++k)
            reinterpret_cast<float4*>(lds_w)[k * 256 + threadIdx.x] = W4[k * 256 + threadIdx.x];
    }
    __syncthreads();

    const unsigned* __restrict__ seg = rbucket + r * RCAP;
    const int  idx    = grp * 64 + lane;
    const bool active = idx < cnt;              // RMW must not run on clamp-duplicated lanes
    const unsigned ent = seg[min(idx, cnt - 1)];
    const int v = (int)(ent >> 16);
    const int s = (int)(ent & 0xFFFF);
    const int obase = wv * 16;

    const float4* __restrict__ hsrc = reinterpret_cast<const float4*>(h + (size_t)s * D);
    float4 hreg[16];
    #pragma unroll
    for (int k = 0; k < 16; ++k) hreg[k] = hsrc[k];

    float acc[16];
    #pragma unroll
    for (int oo = 0; oo < 16; ++oo) acc[oo] = 0.f;

    #pragma unroll
    for (int i4 = 0; i4 < 16; ++i4) {
        #pragma unroll
        for (int ii = 0; ii < 4; ++ii) {
            const float hb = elem(hreg[i4], ii);
            const float4* __restrict__ wr =
                reinterpret_cast<const float4*>(&lds_w[(i4 * 4 + ii) * D + obase]);  // uniform -> broadcast
            #pragma unroll
            for (int q = 0; q < 4; ++q) {
                const float4 w = wr[q];
                acc[q * 4 + 0] = fmaf(hb, w.x, acc[q * 4 + 0]);
                acc[q * 4 + 1] = fmaf(hb, w.y, acc[q * 4 + 1]);
                acc[q * 4 + 2] = fmaf(hb, w.z, acc[q * 4 + 2]);
                acc[q * 4 + 3] = fmaf(hb, w.w, acc[q * 4 + 3]);
            }
        }
    }

    if (active) {
        float4* __restrict__ orow = reinterpret_cast<float4*>(out + (size_t)v * D + obase);
        #pragma unroll
        for (int q = 0; q < 4; ++q) {
            float4 o = orow[q];
            o.x += acc[q * 4 + 0];
            o.y += acc[q * 4 + 1];
            o.z += acc[q * 4 + 2];
            o.w += acc[q * 4 + 3];
            orow[q] = o;
        }
    }
}

extern "C" void kernel_launch(void* const* d_in, const int* in_sizes, int n_in,
                              void* d_out, int out_size, void* d_ws, size_t ws_size,
                              hipStream_t stream) {
    const float* h      = (const float*)d_in[0];
    const int*   edges  = (const int*)d_in[1];
    const float* weight = (const float*)d_in[2];
    const float* wself  = (const float*)d_in[3];
    float* out = (float*)d_out;

    char* ws = (char*)d_ws;
    u64*      packed  = (u64*)ws;
    int*      cursor  = (int*)(ws + WS_CURSOR);
    unsigned* rbucket = (unsigned*)(ws + WS_RBUCKET);

    k_init<<<128, 256, 0, stream>>>(packed, cursor);
    k_scatter_dense<<<SCAT_BLOCKS + DENSE_BLOCKS, 256, 0, stream>>>(edges, h, wself, packed, out);
    k_fill<<<FILL_BLOCKS, 256, 0, stream>>>(packed, cursor, rbucket);
    k_rel<<<NREL * RB2, 256, 0, stream>>>(h, weight, rbucket, cursor, out);
}

// Round 14
// 40.053 us; speedup vs baseline: 1.3120x; 1.3120x over previous
//
#include <hip/hip_runtime.h>
#include <hip/hip_fp16.h>

#define NN 50000
#define NE 100000
#define NREL 64
#define D 64
#define RCAP 1280      // per-relation bucket capacity (expected ~676)
#define SCAP 8192      // self-only bucket capacity (expected ~6766)
#define CSTR 16        // cursor stride in ints (64 B per counter)
#define GPR  20        // group-blocks per relation (covers RCAP/64)
#define SGRP 128       // self-only group-blocks
#define FILL_BLOCKS 128
#define FILL_ITERS  2

typedef unsigned long long u64;

// ws layout (bytes): packed [0,400000) | cursor @512K (65*64B) |
// rbucket @520K (327.7KB) | sbucket @896K (32KB) | h2 @1M (6.4MB)
#define WS_CURSOR  (512 * 1024)
#define WS_RBUCKET (520 * 1024)
#define WS_SBUCKET (896 * 1024)
#define WS_H2      (1024 * 1024)

// init packed/cursor + convert h (f32) -> h2 (half2 pairs)
__global__ __launch_bounds__(256) void k_pre(
    const float* __restrict__ h, u64* __restrict__ packed,
    int* __restrict__ cursor, __half2* __restrict__ h2)
{
    const int t = blockIdx.x * 256 + threadIdx.x;
    const int nthr = gridDim.x * 256;
    for (int i = t; i < NN; i += nthr) packed[i] = 0ull;
    if (t < 65) cursor[t * CSTR] = 0;

    const float2* __restrict__ hf2 = reinterpret_cast<const float2*>(h);
    for (int m = t; m < NN * (D / 2); m += nthr) {
        const float2 p = hf2[m];
        h2[m] = __floats2half2_rn(p.x, p.y);
    }
}

// one 64-bit atomicMax per edge: key = (e+1)<<22 | rel<<16 | src
__global__ void k_scatter(const int* __restrict__ edges, u64* __restrict__ packed) {
    int e = blockIdx.x * blockDim.x + threadIdx.x;
    if (e < NE) {
        int s = edges[e * 3 + 0];
        int r = edges[e * 3 + 1];
        int d = edges[e * 3 + 2];
        u64 key = ((u64)(e + 1) << 22) | ((u64)r << 16) | (u64)s;
        atomicMax(&packed[d], key);
    }
}

// block-aggregated bucket fill: LDS histogram -> 1 global atomic per (block, rel)
__global__ __launch_bounds__(256) void k_fill(
    const u64* __restrict__ packed, int* __restrict__ cursor,
    unsigned* __restrict__ rbucket, unsigned* __restrict__ sbucket)
{
    __shared__ int hcnt[65];
    __shared__ int hbase[65];
    const int t = threadIdx.x;
    if (t < 65) hcnt[t] = 0;
    __syncthreads();

    int      myr[FILL_ITERS];
    int      myslot[FILL_ITERS];
    unsigned myent[FILL_ITERS];

    #pragma unroll
    for (int it = 0; it < FILL_ITERS; ++it) {
        const int v = (blockIdx.x * FILL_ITERS + it) * 256 + t;
        myr[it] = -1;
        if (v < NN) {
            u64 key = packed[v];
            if (key) {
                myr[it]   = (int)((key >> 16) & 63);
                myent[it] = ((unsigned)v << 16) | (unsigned)(key & 0xFFFF);
            } else {
                myr[it]   = 64;
                myent[it] = (unsigned)v;
            }
            myslot[it] = atomicAdd(&hcnt[myr[it]], 1);
        }
    }
    __syncthreads();
    if (t < 65 && hcnt[t] > 0)
        hbase[t] = atomicAdd(&cursor[t * CSTR], hcnt[t]);
    __syncthreads();

    #pragma unroll
    for (int it = 0; it < FILL_ITERS; ++it) {
        const int r = myr[it];
        if (r >= 0) {
            const int p = hbase[r] + myslot[it];
            if (r < 64) { if (p < RCAP) rbucket[r * RCAP + p] = myent[it]; }
            else        { if (p < SCAP) sbucket[p] = myent[it]; }
        }
    }
}

// lane = node; wave = 64 nodes x 16 output cols (4 o-quarter waves / block).
// Weights in LDS as half2 (16 KiB total); inner loop is v_pk_fma_f16.
__global__ __launch_bounds__(256) void k_compute(
    const __half2* __restrict__ h2, const float* __restrict__ weight,
    const float* __restrict__ wself, const unsigned* __restrict__ rbucket,
    const unsigned* __restrict__ sbucket, const int* __restrict__ cursor,
    float* __restrict__ out)
{
    __shared__ __half2 lds_w2[D * 32];   // W[r]    8 KiB
    __shared__ __half2 lds_ws2[D * 32];  // W_self  8 KiB

    const int lane = threadIdx.x & 63;
    const int wv   = threadIdx.x >> 6;      // o-quarter 0..3
    const bool isRel = blockIdx.x < NREL * GPR;

    int r = 64, grp, cnt;
    const unsigned* __restrict__ seg;
    if (isRel) {
        r = blockIdx.x / GPR;
        grp = blockIdx.x % GPR;
        seg = rbucket + r * RCAP;
        cnt = min(cursor[r * CSTR], RCAP);
    } else {
        grp = blockIdx.x - NREL * GPR;
        seg = sbucket;
        cnt = min(cursor[64 * CSTR], SCAP);
    }
    if (grp * 64 >= cnt) return;            // block-uniform, before any sync

    // ---- stage weights as half2 ----
    if (isRel) {
        const float4* __restrict__ W4 = reinterpret_cast<const float4*>(weight + (size_t)r * D * D);
        #pragma unroll
        for (int k = 0; k < 4; ++k) {
            const int idx = k * 256 + threadIdx.x;
            const float4 w = W4[idx];
            lds_w2[2 * idx]     = __floats2half2_rn(w.x, w.y);
            lds_w2[2 * idx + 1] = __floats2half2_rn(w.z, w.w);
        }
    }
    {
        const float4* __restrict__ WS4 = reinterpret_cast<const float4*>(wself);
        #pragma unroll
        for (int k = 0; k < 4; ++k) {
            const int idx = k * 256 + threadIdx.x;
            const float4 w = WS4[idx];
            lds_ws2[2 * idx]     = __floats2half2_rn(w.x, w.y);
            lds_ws2[2 * idx + 1] = __floats2half2_rn(w.z, w.w);
        }
    }
    __syncthreads();

    const unsigned ent = seg[min(grp * 64 + lane, cnt - 1)];  // clamped tail: dup node, same value
    const int v = isRel ? (int)(ent >> 16) : (int)ent;
    const int s = (int)(ent & 0xFFFF);
    const int qoff = wv * 8;               // half2 offset of our 16-col quarter

    __half2 acc2[8];
    #pragma unroll
    for (int q = 0; q < 8; ++q) acc2[q] = __floats2half2_rn(0.f, 0.f);

    // ---- pass 1: agg += h[s] @ W[r]  (rel blocks only) ----
    if (isRel) {
        const float4* __restrict__ hrow = reinterpret_cast<const float4*>(h2 + (size_t)s * 32);
        float4 hbuf[8];
        #pragma unroll
        for (int k = 0; k < 8; ++k) hbuf[k] = hrow[k];

        #pragma unroll
        for (int k = 0; k < 8; ++k) {
            const __half2* hp = reinterpret_cast<const __half2*>(&hbuf[k]);  // 4 half2
            #pragma unroll
            for (int j = 0; j < 4; ++j) {
                const int i0 = k * 8 + j * 2;
                const __half2 blo = __low2half2(hp[j]);    // (h_i0, h_i0)
                const __half2 bhi = __high2half2(hp[j]);   // (h_i0+1, h_i0+1)
                const float4* w0 = reinterpret_cast<const float4*>(&lds_w2[i0 * 32 + qoff]);
                const float4* w1 = reinterpret_cast<const float4*>(&lds_w2[(i0 + 1) * 32 + qoff]);
                const float4 a0 = w0[0], a1 = w0[1], b0 = w1[0], b1 = w1[1];
                const __half2* wa0 = reinterpret_cast<const __half2*>(&a0);
                const __half2* wa1 = reinterpret_cast<const __half2*>(&a1);
                const __half2* wb0 = reinterpret_cast<const __half2*>(&b0);
                const __half2* wb1 = reinterpret_cast<const __half2*>(&b1);
                #pragma unroll
                for (int q = 0; q < 4; ++q) {
                    acc2[q]     = __hfma2(blo, wa0[q], acc2[q]);
                    acc2[q + 4] = __hfma2(blo, wa1[q], acc2[q + 4]);
                }
                #pragma unroll
                for (int q = 0; q < 4; ++q) {
                    acc2[q]     = __hfma2(bhi, wb0[q], acc2[q]);
                    acc2[q + 4] = __hfma2(bhi, wb1[q], acc2[q + 4]);
                }
            }
        }
    }

    // ---- pass 2: self += h[v] @ W_self  (all blocks) ----
    {
        const float4* __restrict__ hrow = reinterpret_cast<const float4*>(h2 + (size_t)v * 32);
        float4 hbuf[8];
        #pragma unroll
        for (int k = 0; k < 8; ++k) hbuf[k] = hrow[k];

        #pragma unroll
        for (int k = 0; k < 8; ++k) {
            const __half2* hp = reinterpret_cast<const __half2*>(&hbuf[k]);
            #pragma unroll
            for (int j = 0; j < 4; ++j) {
                const int i0 = k * 8 + j * 2;
                const __half2 blo = __low2half2(hp[j]);
                const __half2 bhi = __high2half2(hp[j]);
                const float4* w0 = reinterpret_cast<const float4*>(&lds_ws2[i0 * 32 + qoff]);
                const float4* w1 = reinterpret_cast<const float4*>(&lds_ws2[(i0 + 1) * 32 + qoff]);
                const float4 a0 = w0[0], a1 = w0[1], b0 = w1[0], b1 = w1[1];
                const __half2* wa0 = reinterpret_cast<const __half2*>(&a0);
                const __half2* wa1 = reinterpret_cast<const __half2*>(&a1);
                const __half2* wb0 = reinterpret_cast<const __half2*>(&b0);
                const __half2* wb1 = reinterpret_cast<const __half2*>(&b1);
                #pragma unroll
                for (int q = 0; q < 4; ++q) {
                    acc2[q]     = __hfma2(blo, wa0[q], acc2[q]);
                    acc2[q + 4] = __hfma2(blo, wa1[q], acc2[q + 4]);
                }
                #pragma unroll
                for (int q = 0; q < 4; ++q) {
                    acc2[q]     = __hfma2(bhi, wb0[q], acc2[q]);
                    acc2[q + 4] = __hfma2(bhi, wb1[q], acc2[q + 4]);
                }
            }
        }
    }

    // ---- store: convert to f32, 16 contiguous floats per lane ----
    float4* __restrict__ orow = reinterpret_cast<float4*>(out + (size_t)v * D + wv * 16);
    #pragma unroll
    for (int q = 0; q < 4; ++q) {
        const float2 f0 = __half22float2(acc2[2 * q]);
        const float2 f1 = __half22float2(acc2[2 * q + 1]);
        orow[q] = make_float4(f0.x, f0.y, f1.x, f1.y);
    }
}

extern "C" void kernel_launch(void* const* d_in, const int* in_sizes, int n_in,
                              void* d_out, int out_size, void* d_ws, size_t ws_size,
                              hipStream_t stream) {
    const float* h      = (const float*)d_in[0];
    const int*   edges  = (const int*)d_in[1];
    const float* weight = (const float*)d_in[2];
    const float* wself  = (const float*)d_in[3];
    float* out = (float*)d_out;

    char* ws = (char*)d_ws;
    u64*      packed  = (u64*)ws;
    int*      cursor  = (int*)(ws + WS_CURSOR);
    unsigned* rbucket = (unsigned*)(ws + WS_RBUCKET);
    unsigned* sbucket = (unsigned*)(ws + WS_SBUCKET);
    __half2*  h2      = (__half2*)(ws + WS_H2);

    k_pre<<<512, 256, 0, stream>>>(h, packed, cursor, h2);
    k_scatter<<<(NE + 255) / 256, 256, 0, stream>>>(edges, packed);
    k_fill<<<FILL_BLOCKS, 256, 0, stream>>>(packed, cursor, rbucket, sbucket);
    k_compute<<<NREL * GPR + SGRP, 256, 0, stream>>>(h2, weight, wself, rbucket, sbucket, cursor, out);
}

// Round 15
// 33.171 us; speedup vs baseline: 1.5842x; 1.2075x over previous
//
#include <hip/hip_runtime.h>

#define NN 50000
#define NE 100000
#define NREL 64
#define D 64
#define RCAP 1280      // per-relation bucket capacity (expected ~676)
#define SCAP 8192      // self-only bucket capacity (expected ~6766)
#define CSTR 16        // cursor stride in ints (64 B per counter)
#define BR   8         // blocks per relation
#define SBLK 64        // self-only blocks
#define FILL_BLOCKS 128
#define FILL_ITERS  2

typedef unsigned long long u64;
using f16x8 = __attribute__((ext_vector_type(8))) _Float16;
using f32x4 = __attribute__((ext_vector_type(4))) float;

// ws layout (bytes): packed [0,400000) | cursor @512K | rbucket @520K (327.7KB) |
// sbucket @896K (32KB) | h2 (f16) @1M (6.4MB)
#define WS_CURSOR  (512 * 1024)
#define WS_RBUCKET (520 * 1024)
#define WS_SBUCKET (896 * 1024)
#define WS_H2      (1024 * 1024)

struct H4 { _Float16 v[4]; };   // 8-byte pack

// init packed/cursor + convert h (f32) -> h2 (f16)
__global__ __launch_bounds__(256) void k_pre(
    const float* __restrict__ h, u64* __restrict__ packed,
    int* __restrict__ cursor, _Float16* __restrict__ h2)
{
    const int t = blockIdx.x * 256 + threadIdx.x;
    const int nthr = gridDim.x * 256;
    for (int i = t; i < NN; i += nthr) packed[i] = 0ull;
    if (t < 65) cursor[t * CSTR] = 0;

    const float4* __restrict__ hf4 = reinterpret_cast<const float4*>(h);
    H4* __restrict__ o4 = reinterpret_cast<H4*>(h2);
    for (int m = t; m < NN * (D / 4); m += nthr) {
        const float4 p = hf4[m];
        H4 o;
        o.v[0] = (_Float16)p.x; o.v[1] = (_Float16)p.y;
        o.v[2] = (_Float16)p.z; o.v[3] = (_Float16)p.w;
        o4[m] = o;
    }
}

// one 64-bit atomicMax per edge: key = (e+1)<<22 | rel<<16 | src
__global__ void k_scatter(const int* __restrict__ edges, u64* __restrict__ packed) {
    int e = blockIdx.x * blockDim.x + threadIdx.x;
    if (e < NE) {
        int s = edges[e * 3 + 0];
        int r = edges[e * 3 + 1];
        int d = edges[e * 3 + 2];
        u64 key = ((u64)(e + 1) << 22) | ((u64)r << 16) | (u64)s;
        atomicMax(&packed[d], key);
    }
}

// block-aggregated bucket fill: LDS histogram -> 1 global atomic per (block, rel)
__global__ __launch_bounds__(256) void k_fill(
    const u64* __restrict__ packed, int* __restrict__ cursor,
    unsigned* __restrict__ rbucket, unsigned* __restrict__ sbucket)
{
    __shared__ int hcnt[65];
    __shared__ int hbase[65];
    const int t = threadIdx.x;
    if (t < 65) hcnt[t] = 0;
    __syncthreads();

    int      myr[FILL_ITERS];
    int      myslot[FILL_ITERS];
    unsigned myent[FILL_ITERS];

    #pragma unroll
    for (int it = 0; it < FILL_ITERS; ++it) {
        const int v = (blockIdx.x * FILL_ITERS + it) * 256 + t;
        myr[it] = -1;
        if (v < NN) {
            u64 key = packed[v];
            if (key) {
                myr[it]   = (int)((key >> 16) & 63);
                myent[it] = ((unsigned)v << 16) | (unsigned)(key & 0xFFFF);
            } else {
                myr[it]   = 64;
                myent[it] = (unsigned)v;
            }
            myslot[it] = atomicAdd(&hcnt[myr[it]], 1);
        }
    }
    __syncthreads();
    if (t < 65 && hcnt[t] > 0)
        hbase[t] = atomicAdd(&cursor[t * CSTR], hcnt[t]);
    __syncthreads();

    #pragma unroll
    for (int it = 0; it < FILL_ITERS; ++it) {
        const int r = myr[it];
        if (r >= 0) {
            const int p = hbase[r] + myslot[it];
            if (r < 64) { if (p < RCAP) rbucket[r * RCAP + p] = myent[it]; }
            else        { if (p < SCAP) sbucket[p] = myent[it]; }
        }
    }
}

// MFMA compute: per 16-node tile, out[16x64] = Hs @ W[r] + Hv @ WS.
// A-frag (16x16x32_f16): lane l -> row m=l&15, k=(l>>4)*8+j  (16B direct load from h2 row)
// B-frag: lane l -> col n=l&15, k=(l>>4)*8+j                  (built once per block from LDS)
// C/D   : lane l, reg q -> row m=(l>>4)*4+q, col n=l&15       (m89-verified)
__global__ __launch_bounds__(256) void k_compute(
    const _Float16* __restrict__ h2, const float* __restrict__ weight,
    const float* __restrict__ wself, const unsigned* __restrict__ rbucket,
    const unsigned* __restrict__ sbucket, const int* __restrict__ cursor,
    float* __restrict__ out)
{
    __shared__ _Float16 lds_w[D * D];    // W[r]    8 KiB (f16)
    __shared__ _Float16 lds_ws[D * D];   // W_self  8 KiB (f16)

    const int lane = threadIdx.x & 63;
    const int wv   = threadIdx.x >> 6;
    const bool isRel = blockIdx.x < NREL * BR;

    int r = 64, wslot, wstride, cnt;
    const unsigned* __restrict__ seg;
    if (isRel) {
        r = blockIdx.x / BR;
        wslot = (blockIdx.x % BR) * 4 + wv;
        wstride = BR * 4;
        seg = rbucket + r * RCAP;
        cnt = min(cursor[r * CSTR], RCAP);
    } else {
        wslot = (blockIdx.x - NREL * BR) * 4 + wv;
        wstride = SBLK * 4;
        seg = sbucket;
        cnt = min(cursor[64 * CSTR], SCAP);
    }
    if (cnt == 0) return;   // block-uniform

    // ---- stage weights to LDS as f16 ----
    if (isRel) {
        const float4* __restrict__ W4 = reinterpret_cast<const float4*>(weight + (size_t)r * D * D);
        for (int i = threadIdx.x; i < D * D / 4; i += 256) {
            const float4 w = W4[i];
            H4 o; o.v[0]=(_Float16)w.x; o.v[1]=(_Float16)w.y; o.v[2]=(_Float16)w.z; o.v[3]=(_Float16)w.w;
            *reinterpret_cast<H4*>(&lds_w[i * 4]) = o;
        }
    }
    {
        const float4* __restrict__ WS4 = reinterpret_cast<const float4*>(wself);
        for (int i = threadIdx.x; i < D * D / 4; i += 256) {
            const float4 w = WS4[i];
            H4 o; o.v[0]=(_Float16)w.x; o.v[1]=(_Float16)w.y; o.v[2]=(_Float16)w.z; o.v[3]=(_Float16)w.w;
            *reinterpret_cast<H4*>(&lds_ws[i * 4]) = o;
        }
    }
    __syncthreads();

    // ---- build B-frags once per wave (loop-invariant) ----
    const int kbase = (lane >> 4) * 8;
    const int ncol  = lane & 15;

    f16x8 bws[4][2];                       // [n-tile][k-step]
    #pragma unroll
    for (int nt = 0; nt < 4; ++nt)
        #pragma unroll
        for (int ks = 0; ks < 2; ++ks) {
            f16x8 f;
            #pragma unroll
            for (int j = 0; j < 8; ++j)
                f[j] = lds_ws[(ks * 32 + kbase + j) * D + nt * 16 + ncol];
            bws[nt][ks] = f;
        }

    f16x8 bw[4][2];
    if (isRel) {
        #pragma unroll
        for (int nt = 0; nt < 4; ++nt)
            #pragma unroll
            for (int ks = 0; ks < 2; ++ks) {
                f16x8 f;
                #pragma unroll
                for (int j = 0; j < 8; ++j)
                    f[j] = lds_w[(ks * 32 + kbase + j) * D + nt * 16 + ncol];
                bw[nt][ks] = f;
            }
    }

    // ---- tile loop ----
    for (int t = wslot; t * 16 < cnt; t += wstride) {
        const int myidx = min(t * 16 + ncol, cnt - 1);   // this lane's tile row = ncol
        const unsigned ent = seg[myidx];
        const int v = isRel ? (int)(ent >> 16) : (int)ent;
        const int s = (int)(ent & 0xFFFF);

        f32x4 c[4];
        #pragma unroll
        for (int nt = 0; nt < 4; ++nt) c[nt] = (f32x4){0.f, 0.f, 0.f, 0.f};

        // self part: A = h2[v]
        {
            const f16x8 a0 = *reinterpret_cast<const f16x8*>(h2 + (size_t)v * D + kbase);
            const f16x8 a1 = *reinterpret_cast<const f16x8*>(h2 + (size_t)v * D + 32 + kbase);
            #pragma unroll
            for (int nt = 0; nt < 4; ++nt) {
                c[nt] = __builtin_amdgcn_mfma_f32_16x16x32_f16(a0, bws[nt][0], c[nt], 0, 0, 0);
                c[nt] = __builtin_amdgcn_mfma_f32_16x16x32_f16(a1, bws[nt][1], c[nt], 0, 0, 0);
            }
        }
        // rel part: A = h2[s]
        if (isRel) {
            const f16x8 a0 = *reinterpret_cast<const f16x8*>(h2 + (size_t)s * D + kbase);
            const f16x8 a1 = *reinterpret_cast<const f16x8*>(h2 + (size_t)s * D + 32 + kbase);
            #pragma unroll
            for (int nt = 0; nt < 4; ++nt) {
                c[nt] = __builtin_amdgcn_mfma_f32_16x16x32_f16(a0, bw[nt][0], c[nt], 0, 0, 0);
                c[nt] = __builtin_amdgcn_mfma_f32_16x16x32_f16(a1, bw[nt][1], c[nt], 0, 0, 0);
            }
        }

        // store: reg q holds row m=(lane>>4)*4+q, col = ncol
        int vrow[4];
        #pragma unroll
        for (int q = 0; q < 4; ++q)
            vrow[q] = __shfl(v, (lane >> 4) * 4 + q, 64);

        #pragma unroll
        for (int nt = 0; nt < 4; ++nt)
            #pragma unroll
            for (int q = 0; q < 4; ++q)
                out[(size_t)vrow[q] * D + nt * 16 + ncol] = c[nt][q];
    }
}

extern "C" void kernel_launch(void* const* d_in, const int* in_sizes, int n_in,
                              void* d_out, int out_size, void* d_ws, size_t ws_size,
                              hipStream_t stream) {
    const float* h      = (const float*)d_in[0];
    const int*   edges  = (const int*)d_in[1];
    const float* weight = (const float*)d_in[2];
    const float* wself  = (const float*)d_in[3];
    float* out = (float*)d_out;

    char* ws = (char*)d_ws;
    u64*      packed  = (u64*)ws;
    int*      cursor  = (int*)(ws + WS_CURSOR);
    unsigned* rbucket = (unsigned*)(ws + WS_RBUCKET);
    unsigned* sbucket = (unsigned*)(ws + WS_SBUCKET);
    _Float16* h2      = (_Float16*)(ws + WS_H2);

    k_pre<<<512, 256, 0, stream>>>(h, packed, cursor, h2);
    k_scatter<<<(NE + 255) / 256, 256, 0, stream>>>(edges, packed);
    k_fill<<<FILL_BLOCKS, 256, 0, stream>>>(packed, cursor, rbucket, sbucket);
    k_compute<<<NREL * BR + SBLK, 256, 0, stream>>>(h2, weight, wself, rbucket, sbucket, cursor, out);
}